// Round 1
// 121.341 us; speedup vs baseline: 1.0153x; 1.0153x over previous
//
#include <hip/hip_runtime.h>

// HungarianMatcher cost matrix: C[n,t] = 5*L1(box_n,box_t) + 2*(pos-neg)[n,id_t] - 2*GIoU(n,t)
// bs=16, nq=900 -> N=14400 rows; T=1600 targets; nc=91 classes.
// Block = 8 rows x 400 float4-columns, 448 threads. LDS holds only the focal
// class-cost table (2*(pos-neg)+2); pred-box geometry is read with a
// block-uniform address -> scalar loads + SALU, off the vector pipe.
// Enclosing box via min+max identity: ew = (pw+tw) - iw_raw (exact for
// well-formed boxes; reference clamp is a no-op since w,h >= 0).
// R1 changes vs previous best (123.2 us):
//  - PLAIN stores (no nontemporal): let L2/Infinity-Cache absorb the 92 MB
//    output stream; NT was forcing write-around to HBM (~1.6 TB/s effective
//    vs 6.2 TB/s the same region sustains for the harness fill).
//  - t-side loads (tids/tboxes) issued BEFORE the tab build so their global
//    latency hides under the exp/log table work instead of serializing after
//    the barrier.
//  - all 8 row-box scalar loads hoisted ahead of the row loop.
//  - __launch_bounds__(448, 4): cap VGPRs so >=2 blocks/CU are resident.

#define NC 91
#define TT 1600
#define T4 (TT / 4)        // 400 float4 columns
#define ROWS 8
#define NTHREADS 448

typedef float vfloat4 __attribute__((ext_vector_type(4)));

__global__ __launch_bounds__(NTHREADS, 4) void matcher_kernel(
    const float* __restrict__ logits,      // [N, 91]
    const float4* __restrict__ pboxes,     // [N] (cx,cy,w,h)
    const int4* __restrict__ tids,         // [T/4]
    const float4* __restrict__ tboxes,     // [T] (cx,cy,w,h)
    vfloat4* __restrict__ out)             // [N, T/4]
{
    __shared__ float tab[ROWS][NC];        // 2*(pos-neg) + 2 per (row, class)

    const int n0 = blockIdx.x * ROWS;
    const int tid = threadIdx.x;
    const int t4 = tid;
    const bool active = (t4 < T4);

    // --- issue t-side vector loads FIRST; latency hides under tab build ---
    int4 ids = {0, 0, 0, 0};
    float4 tbv[4];
    if (active) {
        ids = tids[t4];
#pragma unroll
        for (int j = 0; j < 4; ++j) tbv[j] = tboxes[t4 * 4 + j];
    }

    // --- per-block precompute: focal class-cost table (scaled/shifted) ---
    for (int i = tid; i < ROWS * NC; i += NTHREADS) {
        const int r = i / NC, c = i - r * NC;
        const float x = logits[(size_t)(n0 + r) * NC + c];
        const float p = __builtin_amdgcn_rcpf(1.f + __expf(-x));  // sigmoid
        const float omp = 1.f - p;
        const float neg = 0.75f * p * p * (-__logf(omp + 1e-8f));
        const float pos = 0.25f * omp * omp * (-__logf(p + 1e-8f));
        tab[r][c] = 2.f * (pos - neg) + 2.f;   // fold COST_CLASS and giou's "+1"
    }
    __syncthreads();

    if (!active) return;

    const int idv[4] = {ids.x, ids.y, ids.z, ids.w};
    float tx0[4], ty0[4], tx1[4], ty1[4], ta[4], tcx[4], tcy[4], tw[4], th[4];
#pragma unroll
    for (int j = 0; j < 4; ++j) {
        const float4 b = tbv[j];
        tcx[j] = b.x; tcy[j] = b.y; tw[j] = b.z; th[j] = b.w;
        tx0[j] = b.x - 0.5f * b.z;
        ty0[j] = b.y - 0.5f * b.w;
        tx1[j] = b.x + 0.5f * b.z;
        ty1[j] = b.y + 0.5f * b.w;
        ta[j] = b.z * b.w;
    }

    // hoist all row boxes: block-uniform addresses -> batched s_load early
    float4 pb[ROWS];
#pragma unroll
    for (int r = 0; r < ROWS; ++r) pb[r] = pboxes[n0 + r];

#pragma unroll
    for (int r = 0; r < ROWS; ++r) {
        const float pcx = pb[r].x, pcy = pb[r].y, pw = pb[r].z, ph = pb[r].w;
        const float px0 = pcx - 0.5f * pw, py0 = pcy - 0.5f * ph;
        const float px1 = pcx + 0.5f * pw, py1 = pcy + 0.5f * ph;
        const float pa  = pw * ph;
        vfloat4 res;
#pragma unroll
        for (int j = 0; j < 4; ++j) {
            // intersection (raw, may be negative)
            const float iwr = fminf(px1, tx1[j]) - fmaxf(px0, tx0[j]);
            const float ihr = fminf(py1, ty1[j]) - fmaxf(py0, ty0[j]);
            const float inter = fmaxf(iwr, 0.f) * fmaxf(ihr, 0.f);
            const float uni = pa + ta[j] - inter;
            // enclosing box via min+max identity (clamp is a no-op: w,h>=0)
            const float ew = (pw + tw[j]) - iwr;
            const float eh = (ph + th[j]) - ihr;
            const float ae = ew * eh;
            const float l1 = fabsf(pcx - tcx[j]) + fabsf(pcy - tcy[j])
                           + fabsf(pw - tw[j]) + fabsf(ph - th[j]);
            // res = 5*L1 + [2*(pos-neg)+2] - 2*inter/uni - 2*uni/ae
            res[j] = 5.f * l1 + tab[r][idv[j]]
                   - 2.f * inter * __builtin_amdgcn_rcpf(uni)
                   - 2.f * uni * __builtin_amdgcn_rcpf(ae);
        }
        out[(size_t)(n0 + r) * T4 + t4] = res;   // plain store: L3 absorbs
    }
}

extern "C" void kernel_launch(void* const* d_in, const int* in_sizes, int n_in,
                              void* d_out, int out_size, void* d_ws, size_t ws_size,
                              hipStream_t stream) {
    const float* logits  = (const float*)d_in[0];
    const float4* pboxes = (const float4*)d_in[1];
    const int4* tids     = (const int4*)d_in[2];
    const float4* tboxes = (const float4*)d_in[3];
    vfloat4* out = (vfloat4*)d_out;
    const int N = in_sizes[1] / 4;  // 14400 rows
    matcher_kernel<<<N / ROWS, NTHREADS, 0, stream>>>(logits, pboxes, tids, tboxes, out);
}